// Round 9
// baseline (3142.205 us; speedup 1.0000x reference)
//
#include <hip/hip_runtime.h>
#include <math.h>

#define BB   2
#define SS   4096
#define DD   512
#define HH   8
#define HDIM 64

typedef short s16x8 __attribute__((ext_vector_type(8)));   // 8 bf16 = 4 VGPR
typedef float f32x4 __attribute__((ext_vector_type(4)));

struct alignas(8) us4 { unsigned short x, y, z, w; };

__device__ __forceinline__ unsigned short f2bf(float f) {
    union { float f; unsigned int u; } cv; cv.f = f;
    const unsigned int u = cv.u;
    return (unsigned short)((u + 0x7fffu + ((u >> 16) & 1u)) >> 16);  // RNE
}

__device__ __forceinline__ s16x8 pack_bf8(float4 a, float4 b) {
    union { s16x8 v; unsigned int u[4]; } r;
    r.u[0] = (unsigned)f2bf(a.x) | ((unsigned)f2bf(a.y) << 16);
    r.u[1] = (unsigned)f2bf(a.z) | ((unsigned)f2bf(a.w) << 16);
    r.u[2] = (unsigned)f2bf(b.x) | ((unsigned)f2bf(b.y) << 16);
    r.u[3] = (unsigned)f2bf(b.z) | ((unsigned)f2bf(b.w) << 16);
    return r.v;
}

// ---------------------------------------------------------------------------
// Kernel 1: QKV projection (fp32 math).  Micro-tile: rows 4*ty+i, cols 4*tx+j
// so epilogue packs ushort4: Q,K (B,H,S,64) coalesced 8B; V^T (B,H,64,S)
// packed along s (4 consecutive rows per thread).
// ---------------------------------------------------------------------------
__global__ __launch_bounds__(256)
void qkv_gemm(const float* __restrict__ x, const float* __restrict__ w,
              const float* __restrict__ bias,
              unsigned short* __restrict__ Qb, unsigned short* __restrict__ Kb,
              unsigned short* __restrict__ Vtb)
{
    __shared__ float As[64][20];
    __shared__ float Bs[16][64];
    const int tid = threadIdx.x;
    const int ty = tid >> 4, tx = tid & 15;
    const int m0 = blockIdx.x * 64;
    const int n0 = blockIdx.y * 64;
    const int N  = 3 * DD;

    float c[4][4] = {};

    for (int k0 = 0; k0 < DD; k0 += 16) {
        {
            const int r  = tid >> 2;
            const int c4 = (tid & 3) * 4;
            *(float4*)&As[r][c4] =
                *(const float4*)&x[(size_t)(m0 + r) * DD + k0 + c4];
            const int br  = tid >> 4;
            const int bc4 = (tid & 15) * 4;
            *(float4*)&Bs[br][bc4] =
                *(const float4*)&w[(size_t)(k0 + br) * N + n0 + bc4];
        }
        __syncthreads();
        #pragma unroll
        for (int kk0 = 0; kk0 < 16; kk0 += 4) {
            float4 a4[4];
            #pragma unroll
            for (int i = 0; i < 4; ++i) a4[i] = *(const float4*)&As[ty * 4 + i][kk0];
            #pragma unroll
            for (int w4 = 0; w4 < 4; ++w4) {
                const float4 bv = *(const float4*)&Bs[kk0 + w4][tx * 4];
                #pragma unroll
                for (int i = 0; i < 4; ++i) {
                    const float av = ((const float*)&a4[i])[w4];
                    c[i][0] = fmaf(av, bv.x, c[i][0]);
                    c[i][1] = fmaf(av, bv.y, c[i][1]);
                    c[i][2] = fmaf(av, bv.z, c[i][2]);
                    c[i][3] = fmaf(av, bv.w, c[i][3]);
                }
            }
        }
        __syncthreads();
    }

    const int h    = n0 / 192;          // 192 = 3*64 cols per head
    const int kind = (n0 % 192) / 64;   // 0=Q 1=K 2=V
    if (kind != 2) {
        unsigned short* dst = kind ? Kb : Qb;
        #pragma unroll
        for (int i = 0; i < 4; ++i) {
            const int t  = m0 + ty * 4 + i;
            const int bb = t >> 12;
            const int s  = t & 4095;
            const int bh = bb * HH + h;
            us4 o;
            o.x = f2bf(c[i][0] + bias[n0 + tx * 4 + 0]);
            o.y = f2bf(c[i][1] + bias[n0 + tx * 4 + 1]);
            o.z = f2bf(c[i][2] + bias[n0 + tx * 4 + 2]);
            o.w = f2bf(c[i][3] + bias[n0 + tx * 4 + 3]);
            *(us4*)&dst[((size_t)bh * SS + s) * HDIM + tx * 4] = o;
        }
    } else {
        const int t0 = m0 + ty * 4;       // 4 consecutive rows, same batch
        const int bb = t0 >> 12;
        const int s0 = t0 & 4095;
        const int bh = bb * HH + h;
        #pragma unroll
        for (int j = 0; j < 4; ++j) {
            const int d = tx * 4 + j;
            const float bz = bias[n0 + d];
            us4 o;
            o.x = f2bf(c[0][j] + bz);
            o.y = f2bf(c[1][j] + bz);
            o.z = f2bf(c[2][j] + bz);
            o.w = f2bf(c[3][j] + bz);
            *(us4*)&Vtb[((size_t)bh * HDIM + d) * SS + s0] = o;   // V^T
        }
    }
}

// ---------------------------------------------------------------------------
// Kernel 2: fused attention, swapped-operand MFMA (S = K x Q so each lane owns
// one q-row).  4 waves x 16 q-rows; per-wave LDS P-tile; no in-loop barriers.
// Phase A: online m/l.  Phase B: recompute S, p=exp(s-m)/l, coalesced f32 prob
// store via LDS, PV MFMA with V^T frags.
// ---------------------------------------------------------------------------
__global__ __launch_bounds__(256)
void attn_fused(const unsigned short* __restrict__ Qb,
                const unsigned short* __restrict__ Kb,
                const unsigned short* __restrict__ Vtb,
                const int* __restrict__ mask,
                float* __restrict__ attn, float* __restrict__ val)
{
    __shared__ unsigned int Mb[SS / 4];       // packed mask bytes, 4 KB
    __shared__ float Pf[4][16][68];           // per-wave P tile, 17.4 KB
    const int tid  = threadIdx.x;
    const int wave = tid >> 6;
    const int lane = tid & 63;
    const int lgrp = lane >> 4;     // 0..3
    const int lcol = lane & 15;     // 0..15 : this lane's q-row within strip
    const int q0   = blockIdx.x * 64;
    const int bh   = blockIdx.y;
    const int b    = bh >> 3;

    const unsigned short* Qh  = Qb  + (size_t)bh * SS * HDIM;
    const unsigned short* Kh  = Kb  + (size_t)bh * SS * HDIM;
    const unsigned short* Vth = Vtb + (size_t)bh * HDIM * SS;
    float* attn_bh = attn + (size_t)bh * SS * SS;
    const int* mrow = mask + b * SS;

    for (int t = tid; t < SS / 4; t += 256) {
        const int4 mv = *(const int4*)&mrow[t * 4];
        Mb[t] = (unsigned)(mv.x & 1) | ((unsigned)(mv.y & 1) << 8)
              | ((unsigned)(mv.z & 1) << 16) | ((unsigned)(mv.w & 1) << 24);
    }
    __syncthreads();   // only barrier in the kernel

    // Q B-frag: lane holds Q[q=lcol][d = lgrp*8+j (+32)]
    const int qrow = q0 + wave * 16 + lcol;
    const s16x8 qf0 = *(const s16x8*)&Qh[(size_t)qrow * HDIM +      lgrp * 8];
    const s16x8 qf1 = *(const s16x8*)&Qh[(size_t)qrow * HDIM + 32 + lgrp * 8];

    float m_ln = -INFINITY, l_ln = 0.f;

    // ---------------- phase A: online max / sumexp ----------------
    for (int kt = 0; kt < 64; ++kt) {
        const int k0 = kt * 64;
        float sv[16];
        #pragma unroll
        for (int nk = 0; nk < 4; ++nk) {
            const size_t krow = (size_t)(k0 + nk * 16 + lcol) * HDIM;
            const s16x8 kf0 = *(const s16x8*)&Kh[krow +      lgrp * 8];
            const s16x8 kf1 = *(const s16x8*)&Kh[krow + 32 + lgrp * 8];
            f32x4 S = {0.f, 0.f, 0.f, 0.f};
            S = __builtin_amdgcn_mfma_f32_16x16x32_bf16(kf0, qf0, S, 0, 0, 0);
            S = __builtin_amdgcn_mfma_f32_16x16x32_bf16(kf1, qf1, S, 0, 0, 0);
            const unsigned mw = Mb[kt * 16 + nk * 4 + lgrp];
            #pragma unroll
            for (int r = 0; r < 4; ++r)
                sv[nk * 4 + r] = ((mw >> (8 * r)) & 0xffu) ? S[r] * 0.125f : -1e9f;
        }
        // in-lane max of 16 (tree), then 2-step cross-group reduce
        float mx[8];
        #pragma unroll
        for (int i = 0; i < 8; ++i) mx[i] = fmaxf(sv[i], sv[i + 8]);
        #pragma unroll
        for (int i = 0; i < 4; ++i) mx[i] = fmaxf(mx[i], mx[i + 4]);
        float tm = fmaxf(fmaxf(mx[0], mx[1]), fmaxf(mx[2], mx[3]));
        tm = fmaxf(tm, __shfl_xor(tm, 16));
        tm = fmaxf(tm, __shfl_xor(tm, 32));
        const float nm = fmaxf(m_ln, tm);
        #pragma unroll
        for (int i = 0; i < 16; ++i) sv[i] = __expf(sv[i] - nm);
        #pragma unroll
        for (int i = 0; i < 8; ++i) sv[i] += sv[i + 8];
        #pragma unroll
        for (int i = 0; i < 4; ++i) sv[i] += sv[i + 4];
        float se = (sv[0] + sv[1]) + (sv[2] + sv[3]);
        se += __shfl_xor(se, 16);
        se += __shfl_xor(se, 32);
        l_ln = l_ln * __expf(m_ln - nm) + se;
        m_ln = nm;
    }
    const float linv = (l_ln > 0.f) ? 1.f / l_ln : 0.f;

    // ---------------- phase B: probs + PV ----------------
    f32x4 acc[4];
    #pragma unroll
    for (int nd = 0; nd < 4; ++nd) acc[nd] = (f32x4){0.f, 0.f, 0.f, 0.f};

    float (*Pw)[68] = Pf[wave];
    const int prow = lane >> 2;
    const int pcol = (lane & 3) * 16;

    for (int kt = 0; kt < 64; ++kt) {
        const int k0 = kt * 64;
        #pragma unroll
        for (int nk = 0; nk < 4; ++nk) {
            const size_t krow = (size_t)(k0 + nk * 16 + lcol) * HDIM;
            const s16x8 kf0 = *(const s16x8*)&Kh[krow +      lgrp * 8];
            const s16x8 kf1 = *(const s16x8*)&Kh[krow + 32 + lgrp * 8];
            f32x4 S = {0.f, 0.f, 0.f, 0.f};
            S = __builtin_amdgcn_mfma_f32_16x16x32_bf16(kf0, qf0, S, 0, 0, 0);
            S = __builtin_amdgcn_mfma_f32_16x16x32_bf16(kf1, qf1, S, 0, 0, 0);
            const unsigned mw = Mb[kt * 16 + nk * 4 + lgrp];
            f32x4 pq;   // 4 consecutive k for this lane's q-row
            pq[0] = ( mw        & 0xffu) ? __expf(S[0] * 0.125f - m_ln) * linv : 0.f;
            pq[1] = ((mw >>  8) & 0xffu) ? __expf(S[1] * 0.125f - m_ln) * linv : 0.f;
            pq[2] = ((mw >> 16) & 0xffu) ? __expf(S[2] * 0.125f - m_ln) * linv : 0.f;
            pq[3] = ((mw >> 24) & 0xffu) ? __expf(S[3] * 0.125f - m_ln) * linv : 0.f;
            *(f32x4*)&Pw[lcol][nk * 16 + lgrp * 4] = pq;     // ds_write_b128
        }
        // P A-frags (f32 -> bf16 pack); compiler inserts lgkmcnt ordering
        const float4 pa00 = *(const float4*)&Pw[lcol][     lgrp * 8];
        const float4 pa01 = *(const float4*)&Pw[lcol][     lgrp * 8 + 4];
        const float4 pa10 = *(const float4*)&Pw[lcol][32 + lgrp * 8];
        const float4 pa11 = *(const float4*)&Pw[lcol][32 + lgrp * 8 + 4];
        const s16x8 pa0 = pack_bf8(pa00, pa01);
        const s16x8 pa1 = pack_bf8(pa10, pa11);
        #pragma unroll
        for (int nd = 0; nd < 4; ++nd) {
            const size_t vrow = (size_t)(nd * 16 + lcol) * SS + k0;
            const s16x8 vf0 = *(const s16x8*)&Vth[vrow +      lgrp * 8];
            const s16x8 vf1 = *(const s16x8*)&Vth[vrow + 32 + lgrp * 8];
            acc[nd] = __builtin_amdgcn_mfma_f32_16x16x32_bf16(pa0, vf0, acc[nd], 0, 0, 0);
            acc[nd] = __builtin_amdgcn_mfma_f32_16x16x32_bf16(pa1, vf1, acc[nd], 0, 0, 0);
        }
        // coalesced f32 prob store (nontemporal: pure streaming output)
        float* gdst = &attn_bh[(size_t)(q0 + wave * 16 + prow) * SS + k0 + pcol];
        #pragma unroll
        for (int u = 0; u < 4; ++u) {
            const f32x4 pv = *(const f32x4*)&Pw[prow][pcol + u * 4];
            __builtin_nontemporal_store(pv, (f32x4*)(gdst + u * 4));
        }
    }

    // epilogue: values (f32) in (B,H,S,64); C rows = q (lgrp*4+r), col = d
    #pragma unroll
    for (int nd = 0; nd < 4; ++nd)
        #pragma unroll
        for (int r = 0; r < 4; ++r)
            val[((size_t)bh * SS + q0 + wave * 16 + lgrp * 4 + r) * HDIM
                + nd * 16 + lcol] = acc[nd][r];
}

// ---------------------------------------------------------------------------
// Kernel 3: o = values @ w_o + b_o   (fp32, values read from (B,H,S,64))
// ---------------------------------------------------------------------------
__global__ __launch_bounds__(256)
void oproj_gemm(const float* __restrict__ val, const float* __restrict__ w,
                const float* __restrict__ bias, float* __restrict__ out)
{
    __shared__ float As[64][20];
    __shared__ float Bs[16][64];
    const int tid = threadIdx.x;
    const int ty = tid >> 4, tx = tid & 15;
    const int m0 = blockIdx.x * 64;
    const int n0 = blockIdx.y * 64;

    float c[4][4] = {};

    for (int k0 = 0; k0 < DD; k0 += 16) {
        {
            const int r   = tid >> 2;
            const int c4  = (tid & 3) * 4;
            const int t   = m0 + r;
            const int bb  = t >> 12;
            const int s   = t & 4095;
            const int head = k0 >> 6;
            const int d    = (k0 & 63) + c4;
            *(float4*)&As[r][c4] =
                *(const float4*)&val[(((size_t)bb * HH + head) * SS + s) * HDIM + d];
            const int br  = tid >> 4;
            const int bc4 = (tid & 15) * 4;
            *(float4*)&Bs[br][bc4] =
                *(const float4*)&w[(size_t)(k0 + br) * DD + n0 + bc4];
        }
        __syncthreads();
        #pragma unroll
        for (int kk0 = 0; kk0 < 16; kk0 += 4) {
            float4 a4[4];
            #pragma unroll
            for (int i = 0; i < 4; ++i) a4[i] = *(const float4*)&As[ty + 16*i][kk0];
            #pragma unroll
            for (int w4 = 0; w4 < 4; ++w4) {
                float bv[4];
                #pragma unroll
                for (int j = 0; j < 4; ++j) bv[j] = Bs[kk0 + w4][tx + 16*j];
                #pragma unroll
                for (int i = 0; i < 4; ++i) {
                    const float av = ((const float*)&a4[i])[w4];
                    #pragma unroll
                    for (int j = 0; j < 4; ++j) c[i][j] = fmaf(av, bv[j], c[i][j]);
                }
            }
        }
        __syncthreads();
    }
    #pragma unroll
    for (int i = 0; i < 4; ++i) {
        const int t = m0 + ty + 16*i;
        #pragma unroll
        for (int j = 0; j < 4; ++j) {
            const int n = n0 + tx + 16*j;
            out[(size_t)t * DD + n] = c[i][j] + bias[n];
        }
    }
}

// ---------------------------------------------------------------------------
extern "C" void kernel_launch(void* const* d_in, const int* in_sizes, int n_in,
                              void* d_out, int out_size, void* d_ws, size_t ws_size,
                              hipStream_t stream)
{
    const float* x     = (const float*)d_in[0];
    const int*   mask  = (const int*)d_in[1];
    const float* w_qkv = (const float*)d_in[2];
    const float* b_qkv = (const float*)d_in[3];
    const float* w_o   = (const float*)d_in[4];
    const float* b_o   = (const float*)d_in[5];

    float* out  = (float*)d_out;
    float* attn = out + (size_t)BB * SS * DD;

    const size_t nqkv = (size_t)BB * HH * SS * HDIM;   // 4,194,304
    unsigned short* Qb  = (unsigned short*)d_ws;        // 8.4 MB each
    unsigned short* Kb  = Qb + nqkv;
    unsigned short* Vtb = Kb + nqkv;
    float*          val = (float*)(Vtb + nqkv);         // 16.8 MB

    qkv_gemm  <<<dim3(128, 24), 256, 0, stream>>>(x, w_qkv, b_qkv, Qb, Kb, Vtb);
    attn_fused<<<dim3(64, 16),  256, 0, stream>>>(Qb, Kb, Vtb, mask, attn, val);
    oproj_gemm<<<dim3(128, 8),  256, 0, stream>>>(val, w_o, b_o, out);
}